// Round 1
// baseline (280.214 us; speedup 1.0000x reference)
//
#include <hip/hip_runtime.h>
#include <hip/hip_bf16.h>
#include <float.h>

// Problem constants
constexpr int B  = 64;
constexpr int C  = 256;
constexpr int HW = 1024;   // 32*32
constexpr int K  = 1024;
constexpr float BETA = 0.25f;
constexpr float NTOT_INV = 1.0f / 16777216.0f;  // 1 / (64*256*32*32)

typedef __attribute__((ext_vector_type(8))) short bf16x8;
typedef __attribute__((ext_vector_type(4))) float floatx4;

union U16 { uint4 u; bf16x8 b; };

__device__ inline unsigned short f2bf(float x) {
    unsigned u = __float_as_uint(x);
    return (unsigned short)((u + 0x7FFFu + ((u >> 16) & 1u)) >> 16);  // RNE
}

// --- kernel 1: emb fp32 -> bf16 (row-major) + esq1[k] = 1 + ||e_k||^2 ---
// also zeroes the loss accumulators (block 0). grid 256 x 256 threads.
__global__ __launch_bounds__(256) void prep_kernel(const float* __restrict__ emb,
                                                   short* __restrict__ emb_bf,
                                                   float* __restrict__ esq1,
                                                   float* __restrict__ acc_loss) {
    if (blockIdx.x == 0 && threadIdx.x < 2) acc_loss[threadIdx.x] = 0.0f;
    const int wid  = threadIdx.x >> 6;
    const int lane = threadIdx.x & 63;
    const int k    = blockIdx.x * 4 + wid;
    const float4 v = *(const float4*)(emb + (size_t)k * C + lane * 4);
    ushort4 pk = { f2bf(v.x), f2bf(v.y), f2bf(v.z), f2bf(v.w) };
    *(ushort4*)(emb_bf + (size_t)k * C + lane * 4) = pk;
    float s = v.x * v.x + v.y * v.y + v.z * v.z + v.w * v.w;
#pragma unroll
    for (int off = 32; off > 0; off >>= 1) s += __shfl_down(s, off, 64);
    if (lane == 0) esq1[k] = 1.0f + s;
}

// --- kernel 2: 4-wave blocks; 64 tokens/block; K split across waves ---
// grid: 1024 blocks x 256 threads. Wave w handles codes [w*256, w*256+256).
__global__ __launch_bounds__(256, 4) void vq_main(const float* __restrict__ z,
                                                  const float* __restrict__ emb,
                                                  const short* __restrict__ emb_bf,
                                                  const float* __restrict__ esq1,
                                                  float* __restrict__ out,
                                                  float* __restrict__ acc_loss) {
    // transpose buffer: [32 ch-blocks][64 tok][8 ch] bf16 = 32 KB
    __shared__ short Zs[32 * 512];
    __shared__ unsigned int warr[4 * 64];   // per-wave packed argmin, per token
    __shared__ float lsum[2];               // block loss partials

    const int tid = threadIdx.x;
    const int wid = tid >> 6;      // wave 0..3
    const int L   = tid & 63;      // lane
    const int q   = L >> 4;        // quad
    const int l15 = L & 15;

    const int bidx = blockIdx.x;
    const int b    = bidx >> 4;           // batch
    const int hw0  = (bidx & 15) * 64;    // position tile base
    const float* zb = z + (size_t)b * C * HW + hw0;

    if (tid == 0) { lsum[0] = 0.0f; lsum[1] = 0.0f; }

    // ---- phase 1: cooperative transpose, wave w does channels [w*64, w*64+64) ----
    // lane = token; 4 channels per iteration, packed 8B write
#pragma unroll 4
    for (int i = 0; i < 16; ++i) {
        const int c = wid * 64 + i * 4;
        float v0 = zb[(size_t)(c + 0) * HW + L];
        float v1 = zb[(size_t)(c + 1) * HW + L];
        float v2 = zb[(size_t)(c + 2) * HW + L];
        float v3 = zb[(size_t)(c + 3) * HW + L];
        ushort4 pk = { f2bf(v0), f2bf(v1), f2bf(v2), f2bf(v3) };
        *(ushort4*)&Zs[(c >> 3) * 512 + L * 8 + (c & 7)] = pk;
    }
    __syncthreads();

    // ---- phase 2: load B-fragments (all 64 tokens x 256 ch) ----
    // zfrag[t][ks]: token = t*16 + l15, ch = ks*32 + q*8 + j
    bf16x8 zfrag[4][8];
#pragma unroll
    for (int t = 0; t < 4; ++t)
#pragma unroll
        for (int ks = 0; ks < 8; ++ks)
            zfrag[t][ks] = *(const bf16x8*)&Zs[(ks * 4 + q) * 512 + (t * 16 + l15) * 8];

    // ---- phase 3: K loop over this wave's 256-code range, A-frags from L2 ----
    unsigned int best[4] = {0xFFFFFFFFu, 0xFFFFFFFFu, 0xFFFFFFFFu, 0xFFFFFFFFu};

    for (int kk = 0; kk < 4; ++kk) {
        const int k0 = wid * 256 + kk * 64;
        floatx4 acc[4][4];   // [m code tile][t token tile]
#pragma unroll
        for (int m = 0; m < 4; ++m)
#pragma unroll
            for (int t = 0; t < 4; ++t) acc[m][t] = (floatx4){0.f, 0.f, 0.f, 0.f};

#pragma unroll
        for (int ks = 0; ks < 8; ++ks) {
            U16 a[4];
#pragma unroll
            for (int m = 0; m < 4; ++m)
                a[m].u = *(const uint4*)(emb_bf + ((size_t)(k0 + m * 16 + l15) << 8) + ks * 32 + q * 8);
#pragma unroll
            for (int m = 0; m < 4; ++m)
#pragma unroll
                for (int t = 0; t < 4; ++t)
                    acc[m][t] = __builtin_amdgcn_mfma_f32_16x16x32_bf16(a[m].b, zfrag[t][ks], acc[m][t], 0, 0, 0);
        }

        // distances + packed argmin (d positive: bits monotone; low 10 bits = code)
#pragma unroll
        for (int m = 0; m < 4; ++m) {
            const float4 eq = *(const float4*)&esq1[k0 + m * 16 + q * 4];
            const float eqa[4] = {eq.x, eq.y, eq.z, eq.w};
#pragma unroll
            for (int r = 0; r < 4; ++r) {
                const unsigned int code = (unsigned int)(k0 + m * 16 + q * 4 + r);
#pragma unroll
                for (int t = 0; t < 4; ++t) {
                    float d = fmaf(-2.0f, acc[m][t][r], eqa[r]);
                    unsigned int u = (__float_as_uint(d) & 0xFFFFFC00u) | code;
                    best[t] = best[t] < u ? best[t] : u;
                }
            }
        }
    }

    // ---- phase 4: butterfly argmin across quads, then across waves via LDS ----
#pragma unroll
    for (int t = 0; t < 4; ++t) {
        unsigned int o = (unsigned int)__shfl_xor((int)best[t], 16, 64);
        best[t] = best[t] < o ? best[t] : o;
        o = (unsigned int)__shfl_xor((int)best[t], 32, 64);
        best[t] = best[t] < o ? best[t] : o;
    }
    // lane L owns token L = (L>>4)*16 + l15 within this wave's code range
    warr[wid * 64 + L] = (q == 0) ? best[0] : (q == 1) ? best[1] : (q == 2) ? best[2] : best[3];
    __syncthreads();

    // ---- phase 5: gather + straight-through out + loss, split over channels ----
    // thread: token = tid&63, channels [wid*64, wid*64+64)
    const int tok = tid & 63;
    unsigned int u0 = warr[tok];
    unsigned int u1 = warr[64 + tok];
    unsigned int u2 = warr[128 + tok];
    unsigned int u3 = warr[192 + tok];
    u0 = u0 < u1 ? u0 : u1;
    u2 = u2 < u3 ? u2 : u3;
    u0 = u0 < u2 ? u0 : u2;
    const int km = (int)(u0 & 1023u);

    const float* erow = emb + (size_t)km * C;
    float s_sq = 0.0f, s_d = 0.0f;
    const size_t base = (size_t)b * C * HW + hw0 + tok;
#pragma unroll 4
    for (int i = 0; i < 16; ++i) {
        const int c = wid * 64 + i * 4;
        float4 ev = *(const float4*)&erow[c];
        const float eva[4] = {ev.x, ev.y, ev.z, ev.w};
#pragma unroll
        for (int j = 0; j < 4; ++j) {
            float zv = z[base + (size_t)(c + j) * HW];
            float diff = eva[j] - zv;                      // z_q - z
            out[base + (size_t)(c + j) * HW] = zv + diff;  // straight-through fwd
            s_sq = fmaf(diff, diff, s_sq);
            s_d += diff;
        }
    }
#pragma unroll
    for (int off = 32; off > 0; off >>= 1) {
        s_sq += __shfl_down(s_sq, off, 64);
        s_d  += __shfl_down(s_d,  off, 64);
    }
    if (L == 0) {
        atomicAdd(&lsum[0], s_sq);
        atomicAdd(&lsum[1], s_d);
    }
    __syncthreads();
    if (tid == 0) {
        atomicAdd(&acc_loss[0], lsum[0]);
        atomicAdd(&acc_loss[1], lsum[1]);
    }
}

// --- kernel 3: finalize scalar loss ---
__global__ void loss_kernel(const float* __restrict__ acc_loss,
                            float* __restrict__ out_loss) {
    out_loss[0] = acc_loss[0] * NTOT_INV + BETA * (acc_loss[1] * NTOT_INV);
}

extern "C" void kernel_launch(void* const* d_in, const int* in_sizes, int n_in,
                              void* d_out, int out_size, void* d_ws, size_t ws_size,
                              hipStream_t stream) {
    const float* z   = (const float*)d_in[0];   // [64,256,32,32]
    const float* emb = (const float*)d_in[1];   // [1024,256]
    float* out = (float*)d_out;                 // [16777216 z_q] + [1 loss]
    float* ws  = (float*)d_ws;
    float* acc  = ws;                               // 2 floats
    float* esq1 = ws + 64;                          // 1024 floats
    short* emb_bf = (short*)(ws + 64 + 1024);       // 1024*256 bf16 = 512 KB

    prep_kernel<<<dim3(K / 4), 256, 0, stream>>>(emb, emb_bf, esq1, acc);
    vq_main<<<dim3(1024), 256, 0, stream>>>(z, emb, emb_bf, esq1, out, acc);
    loss_kernel<<<1, 1, 0, stream>>>(acc, out + (size_t)B * C * HW);
}

// Round 2
// 200.951 us; speedup vs baseline: 1.3944x; 1.3944x over previous
//
#include <hip/hip_runtime.h>
#include <hip/hip_bf16.h>
#include <float.h>

// Problem constants
constexpr int B  = 64;
constexpr int C  = 256;
constexpr int HW = 1024;   // 32*32
constexpr int K  = 1024;
constexpr float BETA = 0.25f;
constexpr float NTOT_INV = 1.0f / 16777216.0f;  // 1 / (64*256*32*32)

typedef __attribute__((ext_vector_type(8))) short bf16x8;
typedef __attribute__((ext_vector_type(4))) float floatx4;

union U16 { uint4 u; bf16x8 b; };

__device__ inline unsigned short f2bf(float x) {
    unsigned u = __float_as_uint(x);
    return (unsigned short)((u + 0x7FFFu + ((u >> 16) & 1u)) >> 16);  // RNE
}

// --- kernel 1: emb fp32 -> bf16 (row-major) + esq1[k] = 1 + ||e_k||^2 ---
// also zeroes the loss accumulators (block 0). grid 256 x 256 threads.
__global__ __launch_bounds__(256) void prep_kernel(const float* __restrict__ emb,
                                                   short* __restrict__ emb_bf,
                                                   float* __restrict__ esq1,
                                                   float* __restrict__ acc_loss) {
    if (blockIdx.x == 0 && threadIdx.x < 2) acc_loss[threadIdx.x] = 0.0f;
    const int wid  = threadIdx.x >> 6;
    const int lane = threadIdx.x & 63;
    const int k    = blockIdx.x * 4 + wid;
    const float4 v = *(const float4*)(emb + (size_t)k * C + lane * 4);
    ushort4 pk = { f2bf(v.x), f2bf(v.y), f2bf(v.z), f2bf(v.w) };
    *(ushort4*)(emb_bf + (size_t)k * C + lane * 4) = pk;
    float s = v.x * v.x + v.y * v.y + v.z * v.z + v.w * v.w;
#pragma unroll
    for (int off = 32; off > 0; off >>= 1) s += __shfl_down(s, off, 64);
    if (lane == 0) esq1[k] = 1.0f + s;
}

// --- kernel 2: 4-wave blocks; 64 tokens/block; K split across waves ---
// grid: 1024 blocks x 256 threads. Wave w handles codes [w*256, w*256+256).
// launch_bounds(256,2): cap 256 unified VGPRs — body needs ~190, must NOT spill
// (launch_bounds(256,4) capped at 128 -> scratch spills -> +380MB HBM, R1 regression)
__global__ __launch_bounds__(256, 2) void vq_main(const float* __restrict__ z,
                                                  const float* __restrict__ emb,
                                                  const short* __restrict__ emb_bf,
                                                  const float* __restrict__ esq1,
                                                  float* __restrict__ out,
                                                  float* __restrict__ acc_loss) {
    // transpose buffer: [32 ch-blocks][64 tok][8 ch] bf16 = 32 KB
    __shared__ short Zs[32 * 512];
    __shared__ unsigned int warr[4 * 64];   // per-wave packed argmin, per token
    __shared__ float lsum[2];               // block loss partials

    const int tid = threadIdx.x;
    const int wid = tid >> 6;      // wave 0..3
    const int L   = tid & 63;      // lane
    const int q   = L >> 4;        // quad
    const int l15 = L & 15;

    const int bidx = blockIdx.x;
    const int b    = bidx >> 4;           // batch
    const int hw0  = (bidx & 15) * 64;    // position tile base
    const float* zb = z + (size_t)b * C * HW + hw0;

    if (tid == 0) { lsum[0] = 0.0f; lsum[1] = 0.0f; }

    // ---- phase 1: cooperative transpose, wave w does channels [w*64, w*64+64) ----
    // lane = token; 4 channels per iteration, packed 8B write
#pragma unroll 4
    for (int i = 0; i < 16; ++i) {
        const int c = wid * 64 + i * 4;
        float v0 = zb[(size_t)(c + 0) * HW + L];
        float v1 = zb[(size_t)(c + 1) * HW + L];
        float v2 = zb[(size_t)(c + 2) * HW + L];
        float v3 = zb[(size_t)(c + 3) * HW + L];
        ushort4 pk = { f2bf(v0), f2bf(v1), f2bf(v2), f2bf(v3) };
        *(ushort4*)&Zs[(c >> 3) * 512 + L * 8 + (c & 7)] = pk;
    }
    __syncthreads();

    // ---- phase 2: load B-fragments (all 64 tokens x 256 ch) ----
    // zfrag[t][ks]: token = t*16 + l15, ch = ks*32 + q*8 + j
    bf16x8 zfrag[4][8];
#pragma unroll
    for (int t = 0; t < 4; ++t)
#pragma unroll
        for (int ks = 0; ks < 8; ++ks)
            zfrag[t][ks] = *(const bf16x8*)&Zs[(ks * 4 + q) * 512 + (t * 16 + l15) * 8];

    // ---- phase 3: K loop over this wave's 256-code range, A-frags from L2 ----
    unsigned int best[4] = {0xFFFFFFFFu, 0xFFFFFFFFu, 0xFFFFFFFFu, 0xFFFFFFFFu};

    for (int kk = 0; kk < 4; ++kk) {
        const int k0 = wid * 256 + kk * 64;
        floatx4 acc[4][4];   // [m code tile][t token tile]
#pragma unroll
        for (int m = 0; m < 4; ++m)
#pragma unroll
            for (int t = 0; t < 4; ++t) acc[m][t] = (floatx4){0.f, 0.f, 0.f, 0.f};

#pragma unroll
        for (int ks = 0; ks < 8; ++ks) {
            U16 a[4];
#pragma unroll
            for (int m = 0; m < 4; ++m)
                a[m].u = *(const uint4*)(emb_bf + ((size_t)(k0 + m * 16 + l15) << 8) + ks * 32 + q * 8);
#pragma unroll
            for (int m = 0; m < 4; ++m)
#pragma unroll
                for (int t = 0; t < 4; ++t)
                    acc[m][t] = __builtin_amdgcn_mfma_f32_16x16x32_bf16(a[m].b, zfrag[t][ks], acc[m][t], 0, 0, 0);
        }

        // distances + packed argmin (d positive: bits monotone; low 10 bits = code)
#pragma unroll
        for (int m = 0; m < 4; ++m) {
            const float4 eq = *(const float4*)&esq1[k0 + m * 16 + q * 4];
            const float eqa[4] = {eq.x, eq.y, eq.z, eq.w};
#pragma unroll
            for (int r = 0; r < 4; ++r) {
                const unsigned int code = (unsigned int)(k0 + m * 16 + q * 4 + r);
#pragma unroll
                for (int t = 0; t < 4; ++t) {
                    float d = fmaf(-2.0f, acc[m][t][r], eqa[r]);
                    unsigned int u = (__float_as_uint(d) & 0xFFFFFC00u) | code;
                    best[t] = best[t] < u ? best[t] : u;
                }
            }
        }
    }

    // ---- phase 4: butterfly argmin across quads, then across waves via LDS ----
#pragma unroll
    for (int t = 0; t < 4; ++t) {
        unsigned int o = (unsigned int)__shfl_xor((int)best[t], 16, 64);
        best[t] = best[t] < o ? best[t] : o;
        o = (unsigned int)__shfl_xor((int)best[t], 32, 64);
        best[t] = best[t] < o ? best[t] : o;
    }
    // lane L owns token L = (L>>4)*16 + l15 within this wave's code range
    warr[wid * 64 + L] = (q == 0) ? best[0] : (q == 1) ? best[1] : (q == 2) ? best[2] : best[3];
    __syncthreads();

    // ---- phase 5: gather + straight-through out + loss, split over channels ----
    // thread: token = tid&63, channels [wid*64, wid*64+64)
    const int tok = tid & 63;
    unsigned int u0 = warr[tok];
    unsigned int u1 = warr[64 + tok];
    unsigned int u2 = warr[128 + tok];
    unsigned int u3 = warr[192 + tok];
    u0 = u0 < u1 ? u0 : u1;
    u2 = u2 < u3 ? u2 : u3;
    u0 = u0 < u2 ? u0 : u2;
    const int km = (int)(u0 & 1023u);

    const float* erow = emb + (size_t)km * C;
    float s_sq = 0.0f, s_d = 0.0f;
    const size_t base = (size_t)b * C * HW + hw0 + tok;
#pragma unroll 4
    for (int i = 0; i < 16; ++i) {
        const int c = wid * 64 + i * 4;
        float4 ev = *(const float4*)&erow[c];
        const float eva[4] = {ev.x, ev.y, ev.z, ev.w};
#pragma unroll
        for (int j = 0; j < 4; ++j) {
            float zv = z[base + (size_t)(c + j) * HW];
            float diff = eva[j] - zv;                      // z_q - z
            out[base + (size_t)(c + j) * HW] = zv + diff;  // straight-through fwd
            s_sq = fmaf(diff, diff, s_sq);
            s_d += diff;
        }
    }
#pragma unroll
    for (int off = 32; off > 0; off >>= 1) {
        s_sq += __shfl_down(s_sq, off, 64);
        s_d  += __shfl_down(s_d,  off, 64);
    }
    if (L == 0) {
        atomicAdd(&lsum[0], s_sq);
        atomicAdd(&lsum[1], s_d);
    }
    __syncthreads();
    if (tid == 0) {
        atomicAdd(&acc_loss[0], lsum[0]);
        atomicAdd(&acc_loss[1], lsum[1]);
    }
}

// --- kernel 3: finalize scalar loss ---
__global__ void loss_kernel(const float* __restrict__ acc_loss,
                            float* __restrict__ out_loss) {
    out_loss[0] = acc_loss[0] * NTOT_INV + BETA * (acc_loss[1] * NTOT_INV);
}

extern "C" void kernel_launch(void* const* d_in, const int* in_sizes, int n_in,
                              void* d_out, int out_size, void* d_ws, size_t ws_size,
                              hipStream_t stream) {
    const float* z   = (const float*)d_in[0];   // [64,256,32,32]
    const float* emb = (const float*)d_in[1];   // [1024,256]
    float* out = (float*)d_out;                 // [16777216 z_q] + [1 loss]
    float* ws  = (float*)d_ws;
    float* acc  = ws;                               // 2 floats
    float* esq1 = ws + 64;                          // 1024 floats
    short* emb_bf = (short*)(ws + 64 + 1024);       // 1024*256 bf16 = 512 KB

    prep_kernel<<<dim3(K / 4), 256, 0, stream>>>(emb, emb_bf, esq1, acc);
    vq_main<<<dim3(1024), 256, 0, stream>>>(z, emb, emb_bf, esq1, out, acc);
    loss_kernel<<<1, 1, 0, stream>>>(acc, out + (size_t)B * C * HW);
}